// Round 3
// baseline (61.992 us; speedup 1.0000x reference)
//
#include <hip/hip_runtime.h>
#include <math.h>

// TransferMatrixMethod: B=256, L=64 (62 inner layers), W=512.
// M_layer = [[cos p, -i sin p/n],[-i n sin p, cos p]] -- real diagonal, pure-
// imaginary off-diagonal; closed under product. Carry as 4 reals [[A,iB],[iC,D]].
//   carry@M(a=cos,b=-sin/n,c=-n sin): A'=A*a-B*c; B'=A*b+B*a; C'=C*a+D*c; D'=D*a-C*b
// Final: E = A+1e-9 + i*B*n_sub ; H = D*n_sub + i*C
//   R = |n_in*E - H|^2 / |n_in*E + H|^2   (division cleared)
//
// R3 vs R2 (R2 ~20us kernel share; suspect full-unroll VGPR spills + no ILP):
//  - chain split into two independent 31-layer products P (layers 1..31) and
//    Q (layers 32..62), interleaved -> 2x ILP, half the serial chain; one
//    structured combine at the end (associativity of the matrix product)
//  - #pragma unroll 4 (bounded) so live sincos values stay ~8, no spills

#define TMM_B 256
#define TMM_L 64
#define TMM_W 512

__global__ __launch_bounds__(256) void tmm_kernel(
    const float* __restrict__ n_layers,   // [B][L]
    const float* __restrict__ d_layers,   // [B][L]
    const float* __restrict__ wavelengths,// [W]
    float* __restrict__ out)              // [B][W]
{
    __shared__ float s_n[TMM_L];
    __shared__ float s_nd[TMM_L];
    __shared__ float s_invn[TMM_L];

    const int b     = blockIdx.x >> 1;           // 2 blocks per batch row
    const int wbase = (blockIdx.x & 1) << 8;     // 0 or 256
    const int tid   = threadIdx.x;

    if (tid < TMM_L) {
        float n = n_layers[b * TMM_L + tid];
        float d = d_layers[b * TMM_L + tid];
        s_n[tid]    = n;
        s_nd[tid]   = n * d;
        s_invn[tid] = __frcp_rn(n + 1e-8f);      // hoisted out of the layer loop
    }
    __syncthreads();

    const int w      = wbase + tid;
    const float lam  = wavelengths[w];
    const float ilam = __frcp_rn(lam);           // phi in revolutions = n*d/lam

    // Two independent structured products (2x ILP, half-length serial chain)
    float Ap = 1.0f, Bp = 0.0f, Cp = 0.0f, Dp = 1.0f;   // layers 1..31
    float Aq = 1.0f, Bq = 0.0f, Cq = 0.0f, Dq = 1.0f;   // layers 32..62

    #pragma unroll 4
    for (int l = 0; l < 31; ++l) {
        {
            const int i      = 1 + l;
            const float n    = s_n[i];                       // LDS broadcast
            const float rev  = s_nd[i] * ilam;               // < 2 revolutions
            const float sp   = __builtin_amdgcn_sinf(rev);   // v_sin_f32
            const float cp   = __builtin_amdgcn_cosf(rev);   // v_cos_f32
            const float bco  = -sp * s_invn[i];
            const float cco  = -n * sp;
            const float A2 = Ap * cp  - Bp * cco;
            const float B2 = Ap * bco + Bp * cp;
            const float C2 = Cp * cp  + Dp * cco;
            const float D2 = Dp * cp  - Cp * bco;
            Ap = A2; Bp = B2; Cp = C2; Dp = D2;
        }
        {
            const int i      = 32 + l;
            const float n    = s_n[i];
            const float rev  = s_nd[i] * ilam;
            const float sp   = __builtin_amdgcn_sinf(rev);
            const float cp   = __builtin_amdgcn_cosf(rev);
            const float bco  = -sp * s_invn[i];
            const float cco  = -n * sp;
            const float A2 = Aq * cp  - Bq * cco;
            const float B2 = Aq * bco + Bq * cp;
            const float C2 = Cq * cp  + Dq * cco;
            const float D2 = Dq * cp  - Cq * bco;
            Aq = A2; Bq = B2; Cq = C2; Dq = D2;
        }
    }

    // Combine: total = P @ Q (same structured-product algebra)
    const float A  = Ap * Aq - Bp * Cq;
    const float Bi = Ap * Bq + Bp * Dq;
    const float Ci = Cp * Aq + Dp * Cq;
    const float D  = Dp * Dq - Cp * Bq;

    const float n_in  = s_n[0];
    const float n_sub = s_n[TMM_L - 1];

    const float E_re = A + 1e-9f;       // E_in + 1e-9 (real part)
    const float E_im = Bi * n_sub;
    const float H_re = D * n_sub;
    const float H_im = Ci;

    const float num_re = n_in * E_re - H_re;
    const float num_im = n_in * E_im - H_im;
    const float den_re = n_in * E_re + H_re;
    const float den_im = n_in * E_im + H_im;

    const float R = (num_re * num_re + num_im * num_im) /
                    (den_re * den_re + den_im * den_im);

    out[b * TMM_W + w] = R;
}

extern "C" void kernel_launch(void* const* d_in, const int* in_sizes, int n_in,
                              void* d_out, int out_size, void* d_ws, size_t ws_size,
                              hipStream_t stream) {
    const float* n_layers    = (const float*)d_in[0];   // 256*64
    const float* d_layers    = (const float*)d_in[1];   // 256*64
    const float* wavelengths = (const float*)d_in[2];   // 512
    float* out = (float*)d_out;                         // 256*512

    dim3 grid(TMM_B * 2);   // 512 blocks: (batch, half-of-W)
    dim3 block(256);
    tmm_kernel<<<grid, block, 0, stream>>>(n_layers, d_layers, wavelengths, out);
}

// Round 4
// 61.812 us; speedup vs baseline: 1.0029x; 1.0029x over previous
//
#include <hip/hip_runtime.h>
#include <math.h>

// TransferMatrixMethod: B=256, L=64 (62 inner layers), W=512.
// Layer matrix [[cos p, -i sin p/n],[-i n sin p, cos p]]: real diagonal,
// pure-imaginary off-diagonal; closed under product -> carry 4 reals
// [[A,iB],[iC,D]].  carry@M(a=cos,b=-sin/n,c=-n sin):
//   A'=A*a-B*c; B'=A*b+B*a; C'=C*a+D*c; D'=D*a-C*b
// Structured product: P@Q = [AA'-BC', AB'+BD', CA'+DC', DD'-CB']
// Final: E = A+1e-9 + i*B*n_sub ; H = D*n_sub + i*C
//   R = |n_in*E - H|^2 / |n_in*E + H|^2
//
// R4 vs R3 (R1-R3 all ~60-64us; kernel suspected occupancy-latency-bound at
// 2 waves/SIMD): 4-way thread split of the 64-slot chain (slots 0 and 63
// padded to identity via nd=0 so all 4 segments run uniform 16 iterations),
// 2-stage __shfl_xor butterfly combine. 8192 waves = 32 waves/CU (full
// occupancy, __launch_bounds__(256,8) caps VGPRs at 64), serial chain /4.

#define TMM_B 256
#define TMM_L 64
#define TMM_W 512

__global__ __launch_bounds__(256, 8) void tmm_kernel(
    const float* __restrict__ n_layers,   // [B][L]
    const float* __restrict__ d_layers,   // [B][L]
    const float* __restrict__ wavelengths,// [W]
    float* __restrict__ out)              // [B][W]
{
    __shared__ float s_n[TMM_L];
    __shared__ float s_nd[TMM_L];
    __shared__ float s_invn[TMM_L];
    __shared__ float s_nin, s_nsub;

    // 2048 blocks: 8 per batch row, each covering 64 wavelengths x 4 segments
    const int b      = blockIdx.x >> 3;
    const int wchunk = blockIdx.x & 7;
    const int tid    = threadIdx.x;
    const int p      = tid >> 2;      // wavelength within chunk (0..63)
    const int seg    = tid & 3;       // chain segment (0..3)

    if (tid < TMM_L) {
        float n = n_layers[b * TMM_L + tid];
        float d = d_layers[b * TMM_L + tid];
        const bool inner = (tid >= 1) && (tid <= TMM_L - 2);
        if (tid == 0)          s_nin  = n;
        if (tid == TMM_L - 1)  s_nsub = n;
        // slots 0 and 63 become identity layers (nd=0 -> sin=0, cos=1)
        s_n[tid]    = inner ? n : 1.0f;
        s_nd[tid]   = inner ? n * d : 0.0f;
        s_invn[tid] = inner ? __frcp_rn(n + 1e-8f) : 1.0f;
    }
    __syncthreads();

    const int w      = (wchunk << 6) + p;
    const float lam  = wavelengths[w];
    const float ilam = __frcp_rn(lam);     // phi in revolutions = n*d/lam

    float A = 1.0f, B = 0.0f, C = 0.0f, D = 1.0f;
    const int base = seg << 4;             // 16 slots per segment

    #pragma unroll 4
    for (int l = 0; l < 16; ++l) {
        const int i      = base + l;
        const float n    = s_n[i];                      // LDS broadcast
        const float rev  = s_nd[i] * ilam;              // < 2 revolutions
        const float sp   = __builtin_amdgcn_sinf(rev);  // v_sin_f32 (rev domain)
        const float cp   = __builtin_amdgcn_cosf(rev);  // v_cos_f32
        const float bco  = -sp * s_invn[i];
        const float cco  = -n * sp;
        const float A2 = A * cp  - B * cco;
        const float B2 = A * bco + B * cp;
        const float C2 = C * cp  + D * cco;
        const float D2 = D * cp  - C * bco;
        A = A2; B = B2; C = C2; D = D2;
    }

    // Butterfly combine (ordered): stage 1 pairs (0,1),(2,3); stage 2 (0,2),(1,3)
    {
        const float Ao = __shfl_xor(A, 1), Bo = __shfl_xor(B, 1);
        const float Co = __shfl_xor(C, 1), Do = __shfl_xor(D, 1);
        const bool hi = (seg & 1);
        const float lA = hi ? Ao : A, lB = hi ? Bo : B, lC = hi ? Co : C, lD = hi ? Do : D;
        const float rA = hi ? A : Ao, rB = hi ? B : Bo, rC = hi ? C : Co, rD = hi ? D : Do;
        A = lA * rA - lB * rC;  B = lA * rB + lB * rD;
        C = lC * rA + lD * rC;  D = lD * rD - lC * rB;
    }
    {
        const float Ao = __shfl_xor(A, 2), Bo = __shfl_xor(B, 2);
        const float Co = __shfl_xor(C, 2), Do = __shfl_xor(D, 2);
        const bool hi = (seg & 2);
        const float lA = hi ? Ao : A, lB = hi ? Bo : B, lC = hi ? Co : C, lD = hi ? Do : D;
        const float rA = hi ? A : Ao, rB = hi ? B : Bo, rC = hi ? C : Co, rD = hi ? D : Do;
        A = lA * rA - lB * rC;  B = lA * rB + lB * rD;
        C = lC * rA + lD * rC;  D = lD * rD - lC * rB;
    }

    const float n_in  = s_nin;
    const float n_sub = s_nsub;

    const float E_re = A + 1e-9f;
    const float E_im = B * n_sub;
    const float H_re = D * n_sub;
    const float H_im = C;

    const float num_re = n_in * E_re - H_re;
    const float num_im = n_in * E_im - H_im;
    const float den_re = n_in * E_re + H_re;
    const float den_im = n_in * E_im + H_im;

    const float R = (num_re * num_re + num_im * num_im) /
                    (den_re * den_re + den_im * den_im);

    if (seg == 0) out[b * TMM_W + w] = R;
}

extern "C" void kernel_launch(void* const* d_in, const int* in_sizes, int n_in,
                              void* d_out, int out_size, void* d_ws, size_t ws_size,
                              hipStream_t stream) {
    const float* n_layers    = (const float*)d_in[0];   // 256*64
    const float* d_layers    = (const float*)d_in[1];   // 256*64
    const float* wavelengths = (const float*)d_in[2];   // 512
    float* out = (float*)d_out;                         // 256*512

    dim3 grid(TMM_B * 8);   // 2048 blocks: (batch, 64-wavelength chunk)
    dim3 block(256);        // 64 wavelengths x 4 chain segments
    tmm_kernel<<<grid, block, 0, stream>>>(n_layers, d_layers, wavelengths, out);
}